// Round 2
// baseline (290.495 us; speedup 1.0000x reference)
//
#include <hip/hip_runtime.h>
#include <hip/hip_bf16.h>

#define Bb 32
#define Ss 2048
#define Hh 1024

typedef __attribute__((ext_vector_type(4))) float f32x4;
typedef __attribute__((ext_vector_type(8))) short s16x8;

#define GAS const __attribute__((address_space(1))) unsigned int
#define LAS __attribute__((address_space(3))) unsigned int

__device__ __forceinline__ unsigned short f2bf(float x) {
  unsigned int u = __float_as_uint(x);
  u = (u + 0x7fffu + ((u >> 16) & 1u)) >> 16;
  return (unsigned short)u;
}

// ---- W_enc fp32 -> bf16, tiled per (ot,kt) 256x64 and PRE-SWIZZLED to match LDS layout ----
// Wswz byte[(ot*16+kt)*32768 + ((r*128 + kc*2) ^ ((r&7)<<4))] = bf16(W[ot*256+r][kt*64+kc])
__global__ void cvt_w_kernel(const float* __restrict__ W, unsigned short* __restrict__ out) {
  int g = blockIdx.x * blockDim.x + threadIdx.x;  // 131072 threads, 8 elems each
  int o = g >> 7;
  int kc8 = (g & 127) << 3;
  const float4* src = reinterpret_cast<const float4*>(W + (size_t)o * Hh + kc8);
  float4 a = src[0], b = src[1];
  union { unsigned short u[8]; uint4 q; } rr;
  rr.u[0] = f2bf(a.x); rr.u[1] = f2bf(a.y); rr.u[2] = f2bf(a.z); rr.u[3] = f2bf(a.w);
  rr.u[4] = f2bf(b.x); rr.u[5] = f2bf(b.y); rr.u[6] = f2bf(b.z); rr.u[7] = f2bf(b.w);
  int ot = o >> 8, r = o & 255, kt = kc8 >> 6, kc = kc8 & 63;
  size_t byte = (size_t)(ot * 16 + kt) * 32768 + (size_t)((r * 128 + kc * 2) ^ ((r & 7) << 4));
  *reinterpret_cast<uint4*>(reinterpret_cast<char*>(out) + byte) = rr.q;
}

// ---- dec_feature[b][o] = dot(dh[b], W_dec[o]) + b_dec[o], fp32, wave per (b,o) ----
__global__ void dec_feat_kernel(const float* __restrict__ dh,
                                const float* __restrict__ Wd,
                                const float* __restrict__ bd,
                                float* __restrict__ out) {
  int gw = blockIdx.x * 4 + (threadIdx.x >> 6);
  int lane = threadIdx.x & 63;
  int b = gw >> 10;
  int o = gw & 1023;
  const float4* x = reinterpret_cast<const float4*>(dh + (size_t)b * Hh);
  const float4* w = reinterpret_cast<const float4*>(Wd + (size_t)o * Hh);
  float acc = 0.f;
#pragma unroll
  for (int it = 0; it < 4; ++it) {
    float4 xa = x[lane + it * 64];
    float4 wa = w[lane + it * 64];
    acc += xa.x * wa.x + xa.y * wa.y + xa.z * wa.z + xa.w * wa.w;
  }
#pragma unroll
  for (int m = 1; m < 64; m <<= 1) acc += __shfl_xor(acc, m, 64);
  if (lane == 0) out[gw] = acc + bd[o];
}

// ---- fused 256x256-tile GEMM (bf16 MFMA) + tanh + v-dot partial reduce ----
// Block: 512 thr = 8 waves (2M x 4N). BM=BN=256, BK=64. LDS 128 KiB double-buffered.
// A reg-staged from fp32 (cvt in-flight), B via global_load_lds from pre-swizzled Wswz.
__global__ void __launch_bounds__(512, 2)
gemm_fused(const float* __restrict__ A,            // enc fp32 [65536][1024]
           const unsigned short* __restrict__ Bw,  // Wswz tiled/swizzled bf16
           const float* __restrict__ decf,         // [32,1024]
           const float* __restrict__ cov,          // [32,2048]
           const float* __restrict__ wcov,         // [1024]
           const float* __restrict__ v,            // [1024]
           float* __restrict__ scores) {           // [32,2048] partial sums
  __shared__ uint4 lds_v[8192];                    // 128 KiB
  char* lds = reinterpret_cast<char*>(lds_v);
  // buf b (b=0,1): A tile at b*65536 (32KB swizzled [256][64] bf16), B tile at b*65536+32768

  int bid = blockIdx.x;
  int swz = (bid & 7) * 128 + (bid >> 3);  // bijective: 1024 % 8 == 0
  const int s_tile = swz >> 2;  // 0..255  (ot fast within XCD chunk -> A-panel L2 reuse)
  const int ot = swz & 3;       // 0..3

  const int tid = threadIdx.x;
  const int lane = tid & 63;
  const int wid = tid >> 6;
  const int wm = wid >> 2, wn = wid & 3;   // 2 x 4 wave grid; per-wave 128x64 output
  const int fr = lane & 15, hi = lane >> 4;

  // A staging: per i in 0..3: row = i*64 + (tid>>3), slot pc = tid&7 (8 fp32 elems)
  const int arow = tid >> 3, apc = tid & 7;
  const float* gA = A + (size_t)(s_tile * 256 + arow) * 1024 + apc * 8;
  const int aswz = (arow & 7) << 4;

  // B staging: 4 x global_load_lds(16B); src pre-swizzled so dest is linear
  const char* gB = reinterpret_cast<const char*>(Bw) + (size_t)ot * 16 * 32768 + tid * 16;

  // frag read offsets (within buf); slot bits are 4..6, swizzle XORs (fr&7)<<4
  const int fswz = (fr & 7) << 4;
  const int aFragBase = (wm * 128 + fr) * 128 + hi * 16;           // + fm*2048 + ks*64
  const int bFragBase = 32768 + (wn * 64 + fr) * 128 + hi * 16;    // + fn*2048 + ks*64

  f32x4 acc[8][4];
#pragma unroll
  for (int i = 0; i < 8; ++i)
#pragma unroll
    for (int j = 0; j < 4; ++j) acc[i][j] = (f32x4){0.f, 0.f, 0.f, 0.f};

  float4 sa[4][2];

#define GLOAD_A(kt) do {                                                         \
    const float* _p = gA + (size_t)(kt) * 64;                                    \
    _Pragma("unroll") for (int i = 0; i < 4; ++i) {                              \
      sa[i][0] = *reinterpret_cast<const float4*>(_p + (size_t)i * 65536);       \
      sa[i][1] = *reinterpret_cast<const float4*>(_p + (size_t)i * 65536 + 4);   \
    }                                                                            \
  } while (0)

#define GLOAD_B(kt, b) do {                                                      \
    _Pragma("unroll") for (int i = 0; i < 4; ++i)                                \
      __builtin_amdgcn_global_load_lds((GAS*)(gB + (size_t)(kt) * 32768 + i * 8192), \
          (LAS*)(lds + (b) * 65536 + 32768 + i * 8192 + tid * 16), 16, 0, 0);    \
  } while (0)

#define AWRITE(b) do {                                                           \
    _Pragma("unroll") for (int i = 0; i < 4; ++i) {                              \
      union { unsigned short u[8]; uint4 q; } w;                                 \
      float4 x = sa[i][0], y = sa[i][1];                                         \
      w.u[0] = f2bf(x.x); w.u[1] = f2bf(x.y); w.u[2] = f2bf(x.z); w.u[3] = f2bf(x.w); \
      w.u[4] = f2bf(y.x); w.u[5] = f2bf(y.y); w.u[6] = f2bf(y.z); w.u[7] = f2bf(y.w); \
      int _byte = (((i * 64 + arow) * 128 + apc * 16) ^ aswz);                   \
      *reinterpret_cast<uint4*>(lds + (b) * 65536 + _byte) = w.q;                \
    }                                                                            \
  } while (0)

#define COMPUTE(b) do {                                                          \
    const char* Lb = lds + (b) * 65536;                                          \
    s16x8 bfr[4][2];                                                             \
    _Pragma("unroll") for (int fn = 0; fn < 4; ++fn)                             \
      _Pragma("unroll") for (int ks = 0; ks < 2; ++ks)                           \
        bfr[fn][ks] = *reinterpret_cast<const s16x8*>(                           \
            Lb + ((bFragBase + fn * 2048 + ks * 64) ^ fswz));                    \
    _Pragma("unroll") for (int mh = 0; mh < 2; ++mh) {                           \
      s16x8 af[4][2];                                                            \
      _Pragma("unroll") for (int fm = 0; fm < 4; ++fm)                           \
        _Pragma("unroll") for (int ks = 0; ks < 2; ++ks)                         \
          af[fm][ks] = *reinterpret_cast<const s16x8*>(                          \
              Lb + ((aFragBase + (mh * 4 + fm) * 2048 + ks * 64) ^ fswz));       \
      _Pragma("unroll") for (int fm = 0; fm < 4; ++fm)                           \
        _Pragma("unroll") for (int fn = 0; fn < 4; ++fn)                         \
          _Pragma("unroll") for (int ks = 0; ks < 2; ++ks)                       \
            acc[mh * 4 + fm][fn] = __builtin_amdgcn_mfma_f32_16x16x32_bf16(      \
                af[fm][ks], bfr[fn][ks], acc[mh * 4 + fm][fn], 0, 0, 0);         \
    }                                                                            \
  } while (0)

  // prologue: stage K-tile 0 into buf 0
  GLOAD_A(0);
  GLOAD_B(0, 0);
  AWRITE(0);
  __syncthreads();

  for (int t = 0; t < 16; ++t) {
    int b = t & 1;
    if (t < 15) {
      GLOAD_A(t + 1);       // issue early: latency hides under MFMAs (T14)
      GLOAD_B(t + 1, b ^ 1);
    }
    COMPUTE(b);
    if (t < 15) AWRITE(b ^ 1);  // vmcnt wait on sa happens here, after compute
    __syncthreads();
  }

#undef GLOAD_A
#undef GLOAD_B
#undef AWRITE
#undef COMPUTE

  // epilogue: C/D layout col(fr)=o, row=(hi*4+reg)=s  [m89-verified, same as R1 kernel]
  const int row0 = s_tile * 256 + wm * 128 + hi * 4;
  const int o0 = ot * 256 + wn * 64 + fr;
  const int bb = s_tile >> 3;

  float vv[4], wv[4], dv[4];
#pragma unroll
  for (int fn = 0; fn < 4; ++fn) {
    int o = o0 + fn * 16;
    vv[fn] = v[o];
    wv[fn] = wcov[o];
    dv[fn] = decf[bb * 1024 + o];
  }

#pragma unroll
  for (int fm = 0; fm < 8; ++fm) {
#pragma unroll
    for (int r = 0; r < 4; ++r) {
      int s_flat = row0 + fm * 16 + r;
      float c = cov[s_flat];
      float sum = 0.f;
#pragma unroll
      for (int fn = 0; fn < 4; ++fn) {
        float x = acc[fm][fn][r] + dv[fn] + c * wv[fn];
        sum += tanhf(x) * vv[fn];
      }
      sum += __shfl_xor(sum, 1, 64);
      sum += __shfl_xor(sum, 2, 64);
      sum += __shfl_xor(sum, 4, 64);
      sum += __shfl_xor(sum, 8, 64);
      if (fr == 0) atomicAdd(&scores[s_flat], sum);
    }
  }
}

// ---- softmax over S=2048 per batch row ----
__global__ void softmax_kernel(const float* __restrict__ scores, float* __restrict__ out) {
  int b = blockIdx.x;
  int tid = threadIdx.x;
  int lane = tid & 63, w = tid >> 6;
  const float* row = scores + (size_t)b * Ss;
  float vals[8];
#pragma unroll
  for (int k = 0; k < 8; ++k) vals[k] = row[tid + k * 256];
  float m = vals[0];
#pragma unroll
  for (int k = 1; k < 8; ++k) m = fmaxf(m, vals[k]);
#pragma unroll
  for (int off = 1; off < 64; off <<= 1) m = fmaxf(m, __shfl_xor(m, off, 64));
  __shared__ float sm[4], ss[4];
  if (lane == 0) sm[w] = m;
  __syncthreads();
  m = fmaxf(fmaxf(sm[0], sm[1]), fmaxf(sm[2], sm[3]));
  float s = 0.f;
#pragma unroll
  for (int k = 0; k < 8; ++k) { vals[k] = __expf(vals[k] - m); s += vals[k]; }
#pragma unroll
  for (int off = 1; off < 64; off <<= 1) s += __shfl_xor(s, off, 64);
  if (lane == 0) ss[w] = s;
  __syncthreads();
  s = ss[0] + ss[1] + ss[2] + ss[3];
  float inv = 1.f / s;
#pragma unroll
  for (int k = 0; k < 8; ++k) out[(size_t)b * Ss + tid + k * 256] = vals[k] * inv;
}

extern "C" void kernel_launch(void* const* d_in, const int* in_sizes, int n_in,
                              void* d_out, int out_size, void* d_ws, size_t ws_size,
                              hipStream_t stream) {
  const float* dh    = (const float*)d_in[0];  // [32,1,1024]
  const float* enc   = (const float*)d_in[1];  // [32,2048,1024]
  const float* cov   = (const float*)d_in[2];  // [32,2048]
  const float* W_enc = (const float*)d_in[3];  // [1024,1024]
  const float* W_dec = (const float*)d_in[4];  // [1024,1024]
  const float* b_dec = (const float*)d_in[5];  // [1024]
  const float* w_cov = (const float*)d_in[6];  // [1024]
  const float* v     = (const float*)d_in[7];  // [1024]
  float* out = (float*)d_out;

  char* ws = (char*)d_ws;
  unsigned short* Wswz = (unsigned short*)ws;               // 2 MB swizzled tiled bf16
  float*          decf = (float*)(ws + 2097152);            // 128 KB
  float*          score = (float*)(ws + 2097152 + 131072);  // 256 KB

  hipMemsetAsync(score, 0, (size_t)Bb * Ss * sizeof(float), stream);
  cvt_w_kernel<<<512, 256, 0, stream>>>(W_enc, Wswz);
  dec_feat_kernel<<<(Bb * Hh) / 4, 256, 0, stream>>>(dh, W_dec, b_dec, decf);
  gemm_fused<<<1024, 512, 0, stream>>>(enc, Wswz, decf, cov, w_cov, v, score);
  softmax_kernel<<<Bb, 256, 0, stream>>>(score, out);
}